// Round 16
// baseline (60.056 us; speedup 1.0000x reference)
//
#include <hip/hip_runtime.h>
#include <hip/hip_bf16.h>

// KAN layer, round 16: r15 + surgical hoist of b1/b2 C-inits (+32 regs, -24 DS).
//  Boundary probe of the 128-reg band: roster = acc 32 + wf1/wf2 32 + woA 8
//  + b1h/b2h 32 + temps ~14 = ~118 total (r13's failed roster minus 36).
//  Per-mti DS reads 13 -> 5 (w0 x2, b0 x2, sx x1). Total DS/wave ~81 -> ~57.
//  All arithmetic identical to r15 (absmax 0.015625 expected bit-exact).
// Swapped GEMM D[n][m]=W[n][k]*H[m][k]; XOR swizzle byte ^= (row&7)<<4.

#define D_EDGES 4096

typedef __attribute__((ext_vector_type(4))) float f32x4;
typedef __attribute__((ext_vector_type(8))) short bf16x8;

__device__ __forceinline__ unsigned pk2(float a, float b) {
    __hip_bfloat162 h = __float22bfloat162_rn(float2{a, b});
    return *reinterpret_cast<unsigned*>(&h);
}

__device__ __forceinline__ bf16x8 mk8(unsigned a, unsigned b, unsigned c, unsigned d) {
    uint4 u{a, b, c, d};
    return __builtin_bit_cast(bf16x8, u);
}

// logical row n -> physical storage row: (c g1 g0 e r1 r0) -> (c e g1 g0 r1 r0)
__device__ __forceinline__ int rho(int n) {
    return (n & 0x23) | ((n & 0x18) >> 1) | ((n & 0x04) << 2);
}

__global__ __launch_bounds__(256, 4) void kan_mfma(
    const float* __restrict__ x,     // (256, 64)
    const float* __restrict__ w0g,   // (D, 64)
    const float* __restrict__ b0g,   // (D, 64)
    const float* __restrict__ w1g,   // (D, 64, 64)
    const float* __restrict__ b1g,   // (D, 64)
    const float* __restrict__ w2g,   // (D, 64, 64)
    const float* __restrict__ b2g,   // (D, 64)
    const float* __restrict__ woutg, // (64, 4096)
    float* __restrict__ outbuf,      // partial (D,256) or y (256,64)
    int atomic_mode)
{
    const int d = blockIdx.x, o = d >> 6, ii = d & 63;
    const int t = threadIdx.x;
    const int lane = t & 63, wv = t >> 6;

    __shared__ __align__(16) unsigned char W1s[64 * 128];    // rho-permuted rows
    __shared__ __align__(16) unsigned char W2s[64 * 128];    // rho-permuted rows
    __shared__ __align__(16) float sx[256];
    __shared__ __align__(16) float sw0[64], sb0[64], sb1[64], sb2[64], swo[64];

    // ---- stage W1, W2 (both row-permuted) -> bf16, swizzled ----
    {
        const int orow = t >> 2, q = t & 3;          // logical row, quarter
        const int prow = rho(orow);                   // physical row
        const unsigned swz  = (unsigned)((prow & 7) << 4);
        const unsigned base = (unsigned)(prow * 128);
        const float* s1 = w1g + (size_t)d * 4096 + orow * 64 + q * 16;
        const float* s2 = w2g + (size_t)d * 4096 + orow * 64 + q * 16;

        float4 a0 = ((const float4*)s1)[0], a1 = ((const float4*)s1)[1];
        float4 a2 = ((const float4*)s1)[2], a3 = ((const float4*)s1)[3];
        uint4 u0 = { pk2(a0.x, a0.y), pk2(a0.z, a0.w), pk2(a1.x, a1.y), pk2(a1.z, a1.w) };
        uint4 u1 = { pk2(a2.x, a2.y), pk2(a2.z, a2.w), pk2(a3.x, a3.y), pk2(a3.z, a3.w) };
        *(uint4*)&W1s[base + ((unsigned)(q * 32)      ^ swz)] = u0;
        *(uint4*)&W1s[base + ((unsigned)(q * 32 + 16) ^ swz)] = u1;

        a0 = ((const float4*)s2)[0]; a1 = ((const float4*)s2)[1];
        a2 = ((const float4*)s2)[2]; a3 = ((const float4*)s2)[3];
        uint4 v0 = { pk2(a0.x, a0.y), pk2(a0.z, a0.w), pk2(a1.x, a1.y), pk2(a1.z, a1.w) };
        uint4 v1 = { pk2(a2.x, a2.y), pk2(a2.z, a2.w), pk2(a3.x, a3.y), pk2(a3.z, a3.w) };
        *(uint4*)&W2s[base + ((unsigned)(q * 32)      ^ swz)] = v0;
        *(uint4*)&W2s[base + ((unsigned)(q * 32 + 16) ^ swz)] = v1;
    }
    sx[t] = x[t * 64 + ii];
    if (t < 64) {
        sw0[t] = w0g[(size_t)d * 64 + t];
        sb0[t] = b0g[(size_t)d * 64 + t];
        sb1[t] = b1g[(size_t)d * 64 + t];
        sb2[t] = b2g[(size_t)d * 64 + t];
        swo[t] = woutg[(size_t)o * 4096 + ii * 64 + t];
    }
    __syncthreads();   // the only block-wide barrier

    const int arow = lane & 15;
    const int kb   = (lane >> 4) * 16;     // byte offset of this lane's 8 k-elems
    const int g8   = (lane >> 4) * 8;      // element offset (8*g)
    const unsigned lswz = (unsigned)((lane & 7) << 4);
    const f32x4 zero4 = { 0.f, 0.f, 0.f, 0.f };

    // ---- hoisted: A-fragments for both layers ----
    bf16x8 wf1[4][2], wf2[4][2];
#pragma unroll
    for (int nt = 0; nt < 4; ++nt)
#pragma unroll
        for (int ks = 0; ks < 2; ++ks) {
            wf1[nt][ks] = *(const bf16x8*)&W1s[(nt * 16 + arow) * 128 +
                            ((unsigned)(ks * 64 + kb) ^ lswz)];
            wf2[nt][ks] = *(const bf16x8*)&W2s[(nt * 16 + arow) * 128 +
                            ((unsigned)(ks * 64 + kb) ^ lswz)];
        }

    // ---- hoisted: wo A-fragment (row 0 = wout slice, rows 1-15 = 0) ----
    bf16x8 woA[2];
#pragma unroll
    for (int ks = 0; ks < 2; ++ks) {
        const int k0 = ks * 32 + g8;
        float4 wa = *(const float4*)&swo[k0];
        float4 wb = *(const float4*)&swo[k0 + 4];
        unsigned u0 = pk2(wa.x, wa.y), u1 = pk2(wa.z, wa.w);
        unsigned u2 = pk2(wb.x, wb.y), u3 = pk2(wb.z, wb.w);
        const bool keep = (arow == 0);
        woA[ks] = mk8(keep ? u0 : 0u, keep ? u1 : 0u,
                      keep ? u2 : 0u, keep ? u3 : 0u);
    }

    // ---- hoisted: b1/b2 C-init vectors at rho-logical offsets (+32 regs) ----
    f32x4 b1h[4], b2h[4];
#pragma unroll
    for (int nt = 0; nt < 4; ++nt) {
        const int bb_ = ((nt >> 1) << 5) + ((nt & 1) << 2) + g8;
        b1h[nt] = *(const f32x4*)&sb1[bb_];
        b2h[nt] = *(const f32x4*)&sb2[bb_];
    }

#pragma unroll
    for (int mti = 0; mti < 4; ++mti) {
        const float xm = sx[wv * 64 + mti * 16 + arow];

        // ---- layer 1: C-init = b1h (registers) ----
        f32x4 a1[4] = { b1h[0], b1h[1], b1h[2], b1h[3] };
        // B-frags from LDS w0/b0 (per-mti reads)
#pragma unroll
        for (int ks = 0; ks < 2; ++ks) {
            const int k0 = ks * 32 + g8;
            float4 wa = *(const float4*)&sw0[k0];
            float4 wb = *(const float4*)&sw0[k0 + 4];
            float4 ba = *(const float4*)&sb0[k0];
            float4 bb = *(const float4*)&sb0[k0 + 4];
            float v0 = fmaxf(fmaf(xm, wa.x, ba.x), 0.f);
            float v1 = fmaxf(fmaf(xm, wa.y, ba.y), 0.f);
            float v2 = fmaxf(fmaf(xm, wa.z, ba.z), 0.f);
            float v3 = fmaxf(fmaf(xm, wa.w, ba.w), 0.f);
            float v4 = fmaxf(fmaf(xm, wb.x, bb.x), 0.f);
            float v5 = fmaxf(fmaf(xm, wb.y, bb.y), 0.f);
            float v6 = fmaxf(fmaf(xm, wb.z, bb.z), 0.f);
            float v7 = fmaxf(fmaf(xm, wb.w, bb.w), 0.f);
            bf16x8 bh = mk8(pk2(v0, v1), pk2(v2, v3), pk2(v4, v5), pk2(v6, v7));
#pragma unroll
            for (int nt = 0; nt < 4; ++nt)
                a1[nt] = __builtin_amdgcn_mfma_f32_16x16x32_bf16(
                    wf1[nt][ks], bh, a1[nt], 0, 0, 0);
        }

        // ---- H1 = relu(a1): pack into layer-2 B-frags (bias already in) ----
        bf16x8 f0 = mk8(
            pk2(fmaxf(a1[0][0], 0.f), fmaxf(a1[0][1], 0.f)),
            pk2(fmaxf(a1[0][2], 0.f), fmaxf(a1[0][3], 0.f)),
            pk2(fmaxf(a1[1][0], 0.f), fmaxf(a1[1][1], 0.f)),
            pk2(fmaxf(a1[1][2], 0.f), fmaxf(a1[1][3], 0.f)));
        bf16x8 f1 = mk8(
            pk2(fmaxf(a1[2][0], 0.f), fmaxf(a1[2][1], 0.f)),
            pk2(fmaxf(a1[2][2], 0.f), fmaxf(a1[2][3], 0.f)),
            pk2(fmaxf(a1[3][0], 0.f), fmaxf(a1[3][1], 0.f)),
            pk2(fmaxf(a1[3][2], 0.f), fmaxf(a1[3][3], 0.f)));

        // ---- layer 2: C-init = b2h (registers; W2 rho-permuted) ----
        f32x4 a2[4] = { b2h[0], b2h[1], b2h[2], b2h[3] };
#pragma unroll
        for (int nt = 0; nt < 4; ++nt) {
            a2[nt] = __builtin_amdgcn_mfma_f32_16x16x32_bf16(
                wf2[nt][0], f0, a2[nt], 0, 0, 0);
            a2[nt] = __builtin_amdgcn_mfma_f32_16x16x32_bf16(
                wf2[nt][1], f1, a2[nt], 0, 0, 0);
        }

        // ---- epilogue: H2 = relu(a2) packs into B-frags over k=n2;
        //      p = wo . H2 via 2 MFMAs against woA (row 0 only) ----
        bf16x8 e0 = mk8(
            pk2(fmaxf(a2[0][0], 0.f), fmaxf(a2[0][1], 0.f)),
            pk2(fmaxf(a2[0][2], 0.f), fmaxf(a2[0][3], 0.f)),
            pk2(fmaxf(a2[1][0], 0.f), fmaxf(a2[1][1], 0.f)),
            pk2(fmaxf(a2[1][2], 0.f), fmaxf(a2[1][3], 0.f)));
        bf16x8 e1 = mk8(
            pk2(fmaxf(a2[2][0], 0.f), fmaxf(a2[2][1], 0.f)),
            pk2(fmaxf(a2[2][2], 0.f), fmaxf(a2[2][3], 0.f)),
            pk2(fmaxf(a2[3][0], 0.f), fmaxf(a2[3][1], 0.f)),
            pk2(fmaxf(a2[3][2], 0.f), fmaxf(a2[3][3], 0.f)));

        f32x4 p3 = zero4;
        p3 = __builtin_amdgcn_mfma_f32_16x16x32_bf16(woA[0], e0, p3, 0, 0, 0);
        p3 = __builtin_amdgcn_mfma_f32_16x16x32_bf16(woA[1], e1, p3, 0, 0, 0);

        // D3[0][m]: lanes 0-15 (g=0), reg 0. m = lane.
        const int b = wv * 64 + mti * 16 + arow;
        if (lane < 16) {
            if (atomic_mode) atomicAdd(&outbuf[b * 64 + o], p3[0]);
            else             outbuf[(size_t)d * 256 + b] = p3[0];
        }
    }
}

// Deterministic reduction over ii: y[b,o] = bout[o] + sum_ii partial[(o*64+ii)*256 + b]
// grid (64 o, 4 bq) x 64 threads -> 256 blocks.
__global__ __launch_bounds__(64) void kan_reduce(
    const float* __restrict__ partial,
    const float* __restrict__ bout,
    float* __restrict__ y)
{
    const int o  = blockIdx.x;                     // 64
    const int b  = blockIdx.y * 64 + threadIdx.x;  // 256
    float acc = bout[o];
    const float* p = partial + (size_t)o * (64 * 256) + b;
#pragma unroll
    for (int i = 0; i < 64; ++i)
        acc += p[i * 256];
    y[b * 64 + o] = acc;
}

__global__ __launch_bounds__(256) void kan_init_out(const float* __restrict__ bout,
                                                    float* __restrict__ y)
{
    const int idx = blockIdx.x * 256 + threadIdx.x;
    y[idx] = bout[idx & 63];
}

extern "C" void kernel_launch(void* const* d_in, const int* in_sizes, int n_in,
                              void* d_out, int out_size, void* d_ws, size_t ws_size,
                              hipStream_t stream) {
    const float* x    = (const float*)d_in[0];
    const float* w0   = (const float*)d_in[1];
    const float* b0   = (const float*)d_in[2];
    const float* w1   = (const float*)d_in[3];
    const float* b1   = (const float*)d_in[4];
    const float* w2   = (const float*)d_in[5];
    const float* b2   = (const float*)d_in[6];
    const float* wout = (const float*)d_in[7];
    const float* bout = (const float*)d_in[8];
    float* y = (float*)d_out;

    const size_t partial_bytes = (size_t)D_EDGES * 256 * sizeof(float); // 4 MB

    if (ws_size >= partial_bytes) {
        float* partial = (float*)d_ws;
        kan_mfma<<<D_EDGES, 256, 0, stream>>>(x, w0, b0, w1, b1, w2, b2, wout, partial, 0);
        kan_reduce<<<dim3(64, 4), 64, 0, stream>>>(partial, bout, y);
    } else {
        kan_init_out<<<64, 256, 0, stream>>>(bout, y);
        kan_mfma<<<D_EDGES, 256, 0, stream>>>(x, w0, b0, w1, b1, w2, b2, wout, y, 1);
    }
}

// Round 17
// 40.657 us; speedup vs baseline: 1.4771x; 1.4771x over previous
//
#include <hip/hip_runtime.h>
#include <hip/hip_bf16.h>

// KAN layer, FINAL (= round-12 champion, 40.7 us bench, clean gates).
//  - One block per edge d (4096 blocks x 256 threads); wave wv owns batch
//    rows [wv*64, wv*64+64).
//  - rho-permuted W1 rows => layer-1 C-frags (after bias+relu+pack) ARE the
//    layer-2 B-frags in registers. No H1 LDS round-trip, zero bank conflicts.
//  - Fragment assembly via __builtin_bit_cast (member-written unions spill).
//  - w0/b0 read from LDS per m-tile (wave-uniform broadcasts) -- the clean
//    64-VGPR configuration; hoisting anything more spills (r13/r14/r16).
// Swapped GEMM D[n][m] = W[n][k]*H[m][k]; XOR swizzle byte ^= (row&7)<<4.
//
// 16-round conclusion: six clean structural variants all plateau at ~50 us
// profiled (~41 us bench): latency-bound at 3-4 waves/SIMD, register wall at
// 64 arch VGPR + AGPR acc, DS/VALU/MFMA pipes all <50%. Barriers, DS-burst
// placement, H1 round-trip, epilogue VALU, and 20% DS cuts all proven null
// by single-variable probes.

#define D_EDGES 4096

typedef __attribute__((ext_vector_type(4))) float f32x4;
typedef __attribute__((ext_vector_type(8))) short bf16x8;

__device__ __forceinline__ unsigned pk2(float a, float b) {
    __hip_bfloat162 h = __float22bfloat162_rn(float2{a, b});
    return *reinterpret_cast<unsigned*>(&h);
}

__device__ __forceinline__ bf16x8 mk8(unsigned a, unsigned b, unsigned c, unsigned d) {
    uint4 u{a, b, c, d};
    return __builtin_bit_cast(bf16x8, u);
}

// logical W1 row -> physical storage row: (c g1 g0 e r1 r0) -> (c e g1 g0 r1 r0)
__device__ __forceinline__ int rho(int n) {
    return (n & 0x23) | ((n & 0x18) >> 1) | ((n & 0x04) << 2);
}

__global__ __launch_bounds__(256, 4) void kan_mfma(
    const float* __restrict__ x,     // (256, 64)
    const float* __restrict__ w0g,   // (D, 64)
    const float* __restrict__ b0g,   // (D, 64)
    const float* __restrict__ w1g,   // (D, 64, 64)
    const float* __restrict__ b1g,   // (D, 64)
    const float* __restrict__ w2g,   // (D, 64, 64)
    const float* __restrict__ b2g,   // (D, 64)
    const float* __restrict__ woutg, // (64, 4096)
    float* __restrict__ outbuf,      // partial (D,256) or y (256,64)
    int atomic_mode)
{
    const int d = blockIdx.x, o = d >> 6, ii = d & 63;
    const int t = threadIdx.x;
    const int lane = t & 63, wv = t >> 6;

    __shared__ __align__(16) unsigned char W1s[64 * 128];    // 8 KB (rows rho-permuted)
    __shared__ __align__(16) unsigned char W2s[64 * 128];    // 8 KB
    __shared__ __align__(16) float sx[256];
    __shared__ __align__(16) float sw0[64], sb0[64], sb1[64], sb2[64], swo[64];

    // ---- stage W1 (row-permuted), W2 -> bf16, swizzled ----
    {
        const int orow = t >> 2, q = t & 3;          // logical row, quarter
        const int prow = rho(orow);                   // physical row for W1
        const unsigned swz1  = (unsigned)((prow & 7) << 4);
        const unsigned base1 = (unsigned)(prow * 128);
        const unsigned swz2  = (unsigned)((orow & 7) << 4);
        const unsigned base2 = (unsigned)(orow * 128);
        const float* s1 = w1g + (size_t)d * 4096 + orow * 64 + q * 16;
        const float* s2 = w2g + (size_t)d * 4096 + orow * 64 + q * 16;

        float4 a0 = ((const float4*)s1)[0], a1 = ((const float4*)s1)[1];
        float4 a2 = ((const float4*)s1)[2], a3 = ((const float4*)s1)[3];
        uint4 u0 = { pk2(a0.x, a0.y), pk2(a0.z, a0.w), pk2(a1.x, a1.y), pk2(a1.z, a1.w) };
        uint4 u1 = { pk2(a2.x, a2.y), pk2(a2.z, a2.w), pk2(a3.x, a3.y), pk2(a3.z, a3.w) };
        *(uint4*)&W1s[base1 + ((unsigned)(q * 32)      ^ swz1)] = u0;
        *(uint4*)&W1s[base1 + ((unsigned)(q * 32 + 16) ^ swz1)] = u1;

        a0 = ((const float4*)s2)[0]; a1 = ((const float4*)s2)[1];
        a2 = ((const float4*)s2)[2]; a3 = ((const float4*)s2)[3];
        uint4 v0 = { pk2(a0.x, a0.y), pk2(a0.z, a0.w), pk2(a1.x, a1.y), pk2(a1.z, a1.w) };
        uint4 v1 = { pk2(a2.x, a2.y), pk2(a2.z, a2.w), pk2(a3.x, a3.y), pk2(a3.z, a3.w) };
        *(uint4*)&W2s[base2 + ((unsigned)(q * 32)      ^ swz2)] = v0;
        *(uint4*)&W2s[base2 + ((unsigned)(q * 32 + 16) ^ swz2)] = v1;
    }
    sx[t] = x[t * 64 + ii];
    if (t < 64) {
        sw0[t] = w0g[(size_t)d * 64 + t];
        sb0[t] = b0g[(size_t)d * 64 + t];
        sb1[t] = b1g[(size_t)d * 64 + t];
        sb2[t] = b2g[(size_t)d * 64 + t];
        swo[t] = woutg[(size_t)o * 4096 + ii * 64 + t];
    }
    __syncthreads();   // the only block-wide barrier

    const int arow = lane & 15;
    const int kb   = (lane >> 4) * 16;     // byte offset of this lane's 8 k-elems
    const int g8   = (lane >> 4) * 8;      // element offset (8*g)
    const unsigned lswz = (unsigned)((lane & 7) << 4);
    const int r0 = (lane >> 4) * 4;
    const f32x4 zero4 = { 0.f, 0.f, 0.f, 0.f };

    // ---- layer-1 A-fragments up-front (needed immediately) ----
    bf16x8 wf1[4][2];
#pragma unroll
    for (int nt = 0; nt < 4; ++nt)
#pragma unroll
        for (int ks = 0; ks < 2; ++ks)
            wf1[nt][ks] = *(const bf16x8*)&W1s[(nt * 16 + arow) * 128 +
                            ((unsigned)(ks * 64 + kb) ^ lswz)];

    bf16x8 wf2[4][2];   // loaded during mti==0 (overlaps compute)

#pragma unroll
    for (int mti = 0; mti < 4; ++mti) {
        const float xm = sx[wv * 64 + mti * 16 + arow];

        // ---- layer 1: B-frag in registers (w0/b0 straight from LDS), MFMA ----
        f32x4 a1[4] = { zero4, zero4, zero4, zero4 };
#pragma unroll
        for (int ks = 0; ks < 2; ++ks) {
            const int k0 = ks * 32 + g8;
            float4 wa = *(const float4*)&sw0[k0];
            float4 wb = *(const float4*)&sw0[k0 + 4];
            float4 ba = *(const float4*)&sb0[k0];
            float4 bb = *(const float4*)&sb0[k0 + 4];
            float v0 = fmaxf(fmaf(xm, wa.x, ba.x), 0.f);
            float v1 = fmaxf(fmaf(xm, wa.y, ba.y), 0.f);
            float v2 = fmaxf(fmaf(xm, wa.z, ba.z), 0.f);
            float v3 = fmaxf(fmaf(xm, wa.w, ba.w), 0.f);
            float v4 = fmaxf(fmaf(xm, wb.x, bb.x), 0.f);
            float v5 = fmaxf(fmaf(xm, wb.y, bb.y), 0.f);
            float v6 = fmaxf(fmaf(xm, wb.z, bb.z), 0.f);
            float v7 = fmaxf(fmaf(xm, wb.w, bb.w), 0.f);
            bf16x8 bh = mk8(pk2(v0, v1), pk2(v2, v3), pk2(v4, v5), pk2(v6, v7));
#pragma unroll
            for (int nt = 0; nt < 4; ++nt)
                a1[nt] = __builtin_amdgcn_mfma_f32_16x16x32_bf16(
                    wf1[nt][ks], bh, a1[nt], 0, 0, 0);
        }

        // ---- wf2 fragment loads, placed after first layer-1 burst ----
        if (mti == 0) {
#pragma unroll
            for (int nt = 0; nt < 4; ++nt)
#pragma unroll
                for (int ks = 0; ks < 2; ++ks)
                    wf2[nt][ks] = *(const bf16x8*)&W2s[(nt * 16 + arow) * 128 +
                                    ((unsigned)(ks * 64 + kb) ^ lswz)];
        }

        // ---- H1 = relu(a1 + b1): pack directly into layer-2 B-frags ----
        // a1[nt][r] is logical hidden unit n = 32*(nt>>1) + 8g + 4*(nt&1) + r.
        unsigned l0, h0, l1, h1, l2, h2, l3, h3;
#define PACK_NT(nt, LO, HI)                                                     \
        {                                                                       \
            const int bb_ = (((nt) >> 1) << 5) + (((nt) & 1) << 2) + g8;        \
            float4 bv = *(const float4*)&sb1[bb_];                              \
            LO = pk2(fmaxf(a1[nt][0] + bv.x, 0.f), fmaxf(a1[nt][1] + bv.y, 0.f)); \
            HI = pk2(fmaxf(a1[nt][2] + bv.z, 0.f), fmaxf(a1[nt][3] + bv.w, 0.f)); \
        }
        PACK_NT(0, l0, h0)
        PACK_NT(1, l1, h1)
        PACK_NT(2, l2, h2)
        PACK_NT(3, l3, h3)
#undef PACK_NT
        bf16x8 f0 = mk8(l0, h0, l1, h1);
        bf16x8 f1 = mk8(l2, h2, l3, h3);

        // ---- layer 2: pure register MFMA ----
        f32x4 a2[4] = { zero4, zero4, zero4, zero4 };
#pragma unroll
        for (int nt = 0; nt < 4; ++nt) {
            a2[nt] = __builtin_amdgcn_mfma_f32_16x16x32_bf16(
                wf2[nt][0], f0, a2[nt], 0, 0, 0);
            a2[nt] = __builtin_amdgcn_mfma_f32_16x16x32_bf16(
                wf2[nt][1], f1, a2[nt], 0, 0, 0);
        }

        // ---- epilogue: p = sum_n2 relu(a2 + b2[n2]) * swo[n2] ----
        float p = 0.f;
#pragma unroll
        for (int nt = 0; nt < 4; ++nt) {
            float4 bv = *(const float4*)&sb2[nt * 16 + r0];
            float4 wo = *(const float4*)&swo[nt * 16 + r0];
            p = fmaf(fmaxf(a2[nt][0] + bv.x, 0.f), wo.x, p);
            p = fmaf(fmaxf(a2[nt][1] + bv.y, 0.f), wo.y, p);
            p = fmaf(fmaxf(a2[nt][2] + bv.z, 0.f), wo.z, p);
            p = fmaf(fmaxf(a2[nt][3] + bv.w, 0.f), wo.w, p);
        }
        p += __shfl_xor(p, 16);
        p += __shfl_xor(p, 32);
        const int b = wv * 64 + mti * 16 + arow;
        if (lane < 16) {
            if (atomic_mode) atomicAdd(&outbuf[b * 64 + o], p);
            else             outbuf[(size_t)d * 256 + b] = p;
        }
    }
}

// Deterministic reduction over ii: y[b,o] = bout[o] + sum_ii partial[(o*64+ii)*256 + b]
// grid (64 o, 4 bq) x 64 threads -> 256 blocks.
__global__ __launch_bounds__(64) void kan_reduce(
    const float* __restrict__ partial,
    const float* __restrict__ bout,
    float* __restrict__ y)
{
    const int o  = blockIdx.x;                     // 64
    const int b  = blockIdx.y * 64 + threadIdx.x;  // 256
    float acc = bout[o];
    const float* p = partial + (size_t)o * (64 * 256) + b;
#pragma unroll
    for (int i = 0; i < 64; ++i)
        acc += p[i * 256];
    y[b * 64 + o] = acc;
}

__global__ __launch_bounds__(256) void kan_init_out(const float* __restrict__ bout,
                                                    float* __restrict__ y)
{
    const int idx = blockIdx.x * 256 + threadIdx.x;
    y[idx] = bout[idx & 63];
}

extern "C" void kernel_launch(void* const* d_in, const int* in_sizes, int n_in,
                              void* d_out, int out_size, void* d_ws, size_t ws_size,
                              hipStream_t stream) {
    const float* x    = (const float*)d_in[0];
    const float* w0   = (const float*)d_in[1];
    const float* b0   = (const float*)d_in[2];
    const float* w1   = (const float*)d_in[3];
    const float* b1   = (const float*)d_in[4];
    const float* w2   = (const float*)d_in[5];
    const float* b2   = (const float*)d_in[6];
    const float* wout = (const float*)d_in[7];
    const float* bout = (const float*)d_in[8];
    float* y = (float*)d_out;

    const size_t partial_bytes = (size_t)D_EDGES * 256 * sizeof(float); // 4 MB

    if (ws_size >= partial_bytes) {
        float* partial = (float*)d_ws;
        kan_mfma<<<D_EDGES, 256, 0, stream>>>(x, w0, b0, w1, b1, w2, b2, wout, partial, 0);
        kan_reduce<<<dim3(64, 4), 64, 0, stream>>>(partial, bout, y);
    } else {
        kan_init_out<<<64, 256, 0, stream>>>(bout, y);
        kan_mfma<<<D_EDGES, 256, 0, stream>>>(x, w0, b0, w1, b1, w2, b2, wout, y, 1);
    }
}